// Round 12
// baseline (168.796 us; speedup 1.0000x reference)
//
#include <hip/hip_runtime.h>
#include <hip/hip_bf16.h>
#include <hip/hip_fp16.h>

// B=16, S=100, D=8192, P=100, W=3
constexpr int Dk   = 8192;
constexpr int Bb   = 16;
constexpr int Ss   = 100;
constexpr int Pp   = 100;
constexpr int MROW = 1632;     // 16 * 102 padded rows
constexpr int NT   = 20;       // n-tiles of 16 -> 320 cols (q|k|v|20 zero)
constexpr int NCC  = 320;
constexpr int NQ   = 304;      // reduced qkv row stride (fp32)
constexpr int KG   = 1024;     // k-groups of 8 (K=8192)
constexpr int KC   = 32;       // K splits (chunk 256 = 8 steps of 32)
constexpr int CH   = 5;        // attn positions per block
constexpr int MBL2 = 26;       // m-blocks of 64 rows

constexpr size_t B_SEG   = (size_t)NT * KG * 128;   // shorts per B segment
constexpr size_t PSTRIDE = (size_t)1664 * NCC;      // halfs per part slice

typedef short s8v __attribute__((ext_vector_type(8)));
typedef float f4v __attribute__((ext_vector_type(4)));

__device__ inline unsigned short f2bf_rne(float f) {
    unsigned u = __float_as_uint(f);
    u += 0x7fffu + ((u >> 16) & 1u);
    return (unsigned short)(u >> 16);
}

// Pack [wq|wk|wv|0] into hi/lo fragment layout [nt][kg][lane16][8].
__global__ __launch_bounds__(256) void pack_b(
    const float* __restrict__ wq, const float* __restrict__ wk,
    const float* __restrict__ wv,
    short* __restrict__ b_hi, short* __restrict__ b_lo) {
    const int id = blockIdx.x * 256 + threadIdx.x;
    const int n  = id % NCC;
    const int kg = id / NCC;
    if (kg >= KG) return;

    const float* w = nullptr; int p = 0;
    if (n < 100)      { w = wq; p = n; }
    else if (n < 200) { w = wk; p = n - 100; }
    else if (n < 300) { w = wv; p = n - 200; }

    s8v hi, lo;
    #pragma unroll
    for (int j = 0; j < 8; ++j) {
        const float v = w ? w[(size_t)(kg * 8 + j) * Pp + p] : 0.0f;
        const unsigned u = __float_as_uint(v);
        hi[j] = (short)(unsigned short)(u >> 16);                 // trunc split
        const float hf = __uint_as_float(u & 0xffff0000u);
        lo[j] = (short)f2bf_rne(v - hf);
    }
    const size_t doff = ((size_t)(n >> 4) * KG + kg) * 128 + (size_t)(n & 15) * 8;
    *(s8v*)(b_hi + doff) = hi;
    *(s8v*)(b_lo + doff) = lo;
}

// Fused QKV GEMM. Grid 832 (26 mb x 32 kc, XCD-pinned); 256 thr = 4 n-waves.
// Block tile 64(M) x 320(N); wave tile 64x80. K-chunk 256 = 8 steps of 32.
//
// ROUND-12: ZERO LDS, ZERO BARRIERS, MAX TLP.
// 12 data points (r0-r11) established: the compiler recycles prefetch
// registers (VGPR pinned ~112-128 even with 256 structurally available),
// serializing each step's loads into latency chains -- and with barriers
// or LDS-forced low occupancy, one wave's chain stalls the whole CU.
// This kernel removes the machinery instead of fighting the allocator:
//  - A fragments load DIRECTLY from global per-lane: the MFMA A-operand's
//    k-dim (8 consecutive d) is contiguous in x; lanes (m, quad 0..3)
//    cover full 128B cache lines. No LDS staging, no transpose barrier.
//    The 4 n-waves re-read the same 8KB/step -> L1 hits.
//  - fp32->bf16hi/lo conversion in-register; lo uses TRUNC (the lo term
//    is 2^-8 of the product; its rounding is invisible at absmax 2^-6).
//  - No __shared__ at all -> 4 blocks/CU at <=128 VGPR: 832 blocks ALL
//    resident (13 waves/CU). Per-wave load serialization overlaps across
//    13 independent waves -> SIMDs become issue-bound, not latency-bound.
__global__ __launch_bounds__(256) void qkv_gemm(
    const float* __restrict__ x, const float* __restrict__ fpad,
    const float* __restrict__ bpad,
    const short* __restrict__ b_hi, const short* __restrict__ b_lo,
    unsigned short* __restrict__ part) {
    const int id   = blockIdx.x;         // 0..831
    const int xcd  = id & 7;             // dispatch round-robin -> XCD
    const int slot = id >> 3;            // 0..103
    const int sub  = slot & 3;           // 0..3
    const int kc   = xcd * 4 + sub;      // 0..31, pinned to this XCD
    const int mb   = slot >> 2;          // 0..25

    const int tid  = threadIdx.x;
    const int w    = tid >> 6;           // wave 0..3 (n-slice)
    const int l    = tid & 63;
    const int m    = l & 15;
    const int quad = l >> 4;

    // ---- A row pointers: lane (m,quad) of frag i reads row mb*64+i*16+m,
    //      k = kc*256 + s*32 + quad*8  (32B contiguous per lane) ----
    const float* ap[4];
    #pragma unroll
    for (int i = 0; i < 4; ++i) {
        const int r = mb * 64 + i * 16 + m;
        const float* p;
        if (r >= MROW) p = fpad;         // junk rows, never read downstream
        else {
            const int b = r / 102, rr = r - b * 102;
            if (rr == 0)        p = fpad + (size_t)b * Dk;
            else if (rr == 101) p = bpad + (size_t)b * Dk;
            else                p = x + ((size_t)b * Ss + (rr - 1)) * Dk;
        }
        ap[i] = p + kc * 256 + quad * 8;
    }

    // ---- B register ping-pong, preload step 0 ----
    s8v bh[2][5], bl[2][5];
    {
        const int kg0 = kc * 32 + quad;
        #pragma unroll
        for (int j = 0; j < 5; ++j) {
            const size_t bo = ((size_t)(w * 5 + j) * KG + kg0) * 128 + (size_t)m * 8;
            bh[0][j] = *(const s8v*)(b_hi + bo);
            bl[0][j] = *(const s8v*)(b_lo + bo);
        }
    }

    f4v acc[4][5];
    #pragma unroll
    for (int i = 0; i < 4; ++i)
        #pragma unroll
        for (int j = 0; j < 5; ++j) {
            f4v z = {0.f, 0.f, 0.f, 0.f};
            acc[i][j] = z;
        }

    #pragma unroll
    for (int s = 0; s < 8; ++s) {
        const int cur = s & 1, nxt = cur ^ 1;

        // A loads for THIS step (8x float4, lane-direct, L1-friendly)
        f4v a0[4], a1[4];
        #pragma unroll
        for (int i = 0; i < 4; ++i) {
            a0[i] = *(const f4v*)(ap[i] + s * 32);
            a1[i] = *(const f4v*)(ap[i] + s * 32 + 4);
        }

        // B prefetch for NEXT step
        if (s < 7) {
            const int kgn = kc * 32 + (s + 1) * 4 + quad;
            #pragma unroll
            for (int j = 0; j < 5; ++j) {
                const size_t bo = ((size_t)(w * 5 + j) * KG + kgn) * 128 + (size_t)m * 8;
                bh[nxt][j] = *(const s8v*)(b_hi + bo);
                bl[nxt][j] = *(const s8v*)(b_lo + bo);
            }
        }

        // convert A in-register: hi = trunc top16; lo = trunc(v - hi_f)
        s8v ah[4], al[4];
        #pragma unroll
        for (int i = 0; i < 4; ++i) {
            #pragma unroll
            for (int jj = 0; jj < 4; ++jj) {
                const unsigned u0 = __float_as_uint(a0[i][jj]);
                ah[i][jj] = (short)(unsigned short)(u0 >> 16);
                const float t0 = a0[i][jj] - __uint_as_float(u0 & 0xffff0000u);
                al[i][jj] = (short)(unsigned short)(__float_as_uint(t0) >> 16);
                const unsigned u1 = __float_as_uint(a1[i][jj]);
                ah[i][4 + jj] = (short)(unsigned short)(u1 >> 16);
                const float t1 = a1[i][jj] - __uint_as_float(u1 & 0xffff0000u);
                al[i][4 + jj] = (short)(unsigned short)(__float_as_uint(t1) >> 16);
            }
        }

        // 60 MFMAs
        #pragma unroll
        for (int j = 0; j < 5; ++j) {
            const s8v bhv = bh[cur][j], blv = bl[cur][j];
            #pragma unroll
            for (int i = 0; i < 4; ++i)
                acc[i][j] = __builtin_amdgcn_mfma_f32_16x16x32_bf16(ah[i], bhv, acc[i][j], 0, 0, 0);
            #pragma unroll
            for (int i = 0; i < 4; ++i)
                acc[i][j] = __builtin_amdgcn_mfma_f32_16x16x32_bf16(al[i], bhv, acc[i][j], 0, 0, 0);
            #pragma unroll
            for (int i = 0; i < 4; ++i)
                acc[i][j] = __builtin_amdgcn_mfma_f32_16x16x32_bf16(ah[i], blv, acc[i][j], 0, 0, 0);
        }
    }

    // store fp16 partials, row-major [kc][row][col]
    unsigned short* __restrict__ pout = part + (size_t)kc * PSTRIDE;
    #pragma unroll
    for (int i = 0; i < 4; ++i) {
        #pragma unroll
        for (int j = 0; j < 5; ++j) {
            const int col  = (w * 5 + j) * 16 + m;
            const int row0 = mb * 64 + i * 16 + quad * 4;
            #pragma unroll
            for (int r = 0; r < 4; ++r)
                pout[(size_t)(row0 + r) * NCC + col] =
                    __half_as_ushort(__float2half(acc[i][j][r]));
        }
    }
}

// Reduce KC fp16 partial slices -> fp32 qkv (stride 304).
// Grid 260 x 256; thread = (row, 8-col group): 32x 16B loads, 2x f32x4 stores.
__global__ __launch_bounds__(256) void reduce_k(
    const unsigned short* __restrict__ part, float* __restrict__ qkv) {
    const int t = blockIdx.x * 256 + threadIdx.x;   // 0..66559
    const int row = t / 40;
    const int col0 = (t - row * 40) * 8;
    const size_t base = (size_t)row * NCC + col0;

    float sum[8] = {0.f, 0.f, 0.f, 0.f, 0.f, 0.f, 0.f, 0.f};
    #pragma unroll
    for (int k = 0; k < KC; ++k) {
        const s8v u = *(const s8v*)(part + (size_t)k * PSTRIDE + base);
        #pragma unroll
        for (int ii = 0; ii < 8; ++ii)
            sum[ii] += __half2float(__ushort_as_half((unsigned short)u[ii]));
    }
    if (col0 < NQ) {
        f4v a = {sum[0], sum[1], sum[2], sum[3]};
        f4v b = {sum[4], sum[5], sum[6], sum[7]};
        *(f4v*)(qkv + (size_t)row * NQ + col0)     = a;
        *(f4v*)(qkv + (size_t)row * NQ + col0 + 4) = b;
    }
}

// Attention on reduced fp32 qkv. Block = (b, chunk of 5 positions); grid 320.
__global__ __launch_bounds__(256) void attn3(
    const float* __restrict__ qkv, float* __restrict__ out) {
    const int blk = blockIdx.x;          // 0..319
    const int b  = blk / (Ss / CH);
    const int c  = blk % (Ss / CH);
    const int s0 = c * CH;
    const int tid = threadIdx.x;

    __shared__ float red[CH + 2][304];   // rows s0..s0+6, cols 0..299
    __shared__ float sc[CH][3];

    for (int idx = tid; idx < (CH + 2) * 300; idx += 256) {
        const int row = idx / 300, col = idx % 300;
        red[row][col] = qkv[(size_t)(b * 102 + s0 + row) * NQ + col];
    }
    __syncthreads();

    // 15 score dots, one per 16-lane group: (ss,u): Q[ss+1].K[ss+u]
    if (tid < CH * 3 * 16) {
        const int d = tid >> 4, g = tid & 15;
        const int ss = d / 3, u = d % 3;
        float ps = 0.0f;
        #pragma unroll
        for (int t = 0; t < 7; ++t) {
            const int p = g + t * 16;
            if (p < Pp) ps += red[ss + 1][p] * red[ss + u][100 + p];
        }
        #pragma unroll
        for (int off = 8; off > 0; off >>= 1) ps += __shfl_down(ps, off, 16);
        if (g == 0) sc[ss][u] = ps;
    }
    __syncthreads();

    for (int idx = tid; idx < CH * Pp; idx += 256) {
        const int ss = idx / Pp, p = idx % Pp;
        const float a0 = sc[ss][0], a1 = sc[ss][1], a2 = sc[ss][2];
        const float mx = fmaxf(a0, fmaxf(a1, a2));
        const float e0 = __expf(a0 - mx), e1 = __expf(a1 - mx), e2 = __expf(a2 - mx);
        const float inv = 1.0f / (e0 + e1 + e2);
        out[(size_t)(b * Ss + s0 + ss) * Pp + p] =
            inv * (e0 * red[ss][200 + p] + e1 * red[ss + 1][200 + p] +
                   e2 * red[ss + 2][200 + p]);
    }
}

extern "C" void kernel_launch(void* const* d_in, const int* in_sizes, int n_in,
                              void* d_out, int out_size, void* d_ws, size_t ws_size,
                              hipStream_t stream) {
    const float* x    = (const float*)d_in[0];
    const float* wq   = (const float*)d_in[1];
    const float* wk   = (const float*)d_in[2];
    const float* wv   = (const float*)d_in[3];
    const float* fpad = (const float*)d_in[4];
    const float* bpad = (const float*)d_in[5];
    float* out = (float*)d_out;

    short* b_hi = (short*)d_ws;                              // 5.24 MB
    short* b_lo = b_hi + B_SEG;                              // 5.24 MB
    unsigned short* part = (unsigned short*)(b_lo + B_SEG);  // 32*1664*320 fp16 = 34.1 MB
    float* qkv = (float*)(part + (size_t)KC * PSTRIDE);      // 1664*304 fp32 = 2.0 MB
    // total ws ~46.6 MB; all buffers fully overwritten, no zeroing needed

    pack_b<<<(NCC * KG) / 256, 256, 0, stream>>>(wq, wk, wv, b_hi, b_lo);
    qkv_gemm<<<MBL2 * KC, 256, 0, stream>>>(x, fpad, bpad, b_hi, b_lo, part);
    reduce_k<<<260, 256, 0, stream>>>(part, qkv);
    attn3<<<Bb * (Ss / CH), 256, 0, stream>>>(qkv, out);
}

// Round 13
// 131.338 us; speedup vs baseline: 1.2852x; 1.2852x over previous
//
#include <hip/hip_runtime.h>
#include <hip/hip_bf16.h>
#include <hip/hip_fp16.h>

// B=16, S=100, D=8192, P=100, W=3
constexpr int Dk   = 8192;
constexpr int Bb   = 16;
constexpr int Ss   = 100;
constexpr int Pp   = 100;
constexpr int MROW = 1632;     // 16 * 102 padded rows
constexpr int NT   = 20;       // n-tiles of 16 -> 320 cols (q|k|v|20 zero)
constexpr int NCC  = 320;
constexpr int KG   = 1024;     // k-groups of 8 (K=8192)
constexpr int KC   = 16;       // K splits (chunk 512 = 16 steps of 32)
constexpr int CH   = 5;        // attn positions per block
constexpr int MBL2 = 26;       // m-blocks of 64 rows

constexpr size_t B_SEG   = (size_t)NT * KG * 128;   // shorts per B segment
constexpr size_t PSTRIDE = (size_t)1664 * NCC;      // halfs per part slice

typedef short s8v __attribute__((ext_vector_type(8)));
typedef float f4v __attribute__((ext_vector_type(4)));

__device__ inline unsigned short f2bf_rne(float f) {
    unsigned u = __float_as_uint(f);
    u += 0x7fffu + ((u >> 16) & 1u);
    return (unsigned short)(u >> 16);
}

// Pack [wq|wk|wv|0] into hi/lo fragment layout [nt][kg][lane16][8].
__global__ __launch_bounds__(256) void pack_b(
    const float* __restrict__ wq, const float* __restrict__ wk,
    const float* __restrict__ wv,
    short* __restrict__ b_hi, short* __restrict__ b_lo) {
    const int id = blockIdx.x * 256 + threadIdx.x;
    const int n  = id % NCC;
    const int kg = id / NCC;
    if (kg >= KG) return;

    const float* w = nullptr; int p = 0;
    if (n < 100)      { w = wq; p = n; }
    else if (n < 200) { w = wk; p = n - 100; }
    else if (n < 300) { w = wv; p = n - 200; }

    s8v hi, lo;
    #pragma unroll
    for (int j = 0; j < 8; ++j) {
        const float v = w ? w[(size_t)(kg * 8 + j) * Pp + p] : 0.0f;
        const unsigned u = __float_as_uint(v);
        hi[j] = (short)(unsigned short)(u >> 16);                 // trunc split
        const float hf = __uint_as_float(u & 0xffff0000u);
        lo[j] = (short)f2bf_rne(v - hf);
    }
    const size_t doff = ((size_t)(n >> 4) * KG + kg) * 128 + (size_t)(n & 15) * 8;
    *(s8v*)(b_hi + doff) = hi;
    *(s8v*)(b_lo + doff) = lo;
}

// Fused QKV GEMM — REVERTED to the round-3 configuration, the measured best
// across 14 structural variants (40.7 us; LDS-ring 52, barrier-free 47,
// waves_per_eu 56, zero-LDS 75-80). Grid 416 (26 mb x 16 kc, XCD-pinned);
// 256 thr = 4 waves. Block tile 64(M) x 320(N); wave tile 64x80.
// K-chunk 512 = 16 steps of 32. Per step: A reg-ring consume + convert ->
// LDS dbuf publish (lgkmcnt-only barrier), B reg stream, 60 MFMAs.
__global__ __launch_bounds__(256, 2) void qkv_gemm(
    const float* __restrict__ x, const float* __restrict__ fpad,
    const float* __restrict__ bpad,
    const short* __restrict__ b_hi, const short* __restrict__ b_lo,
    unsigned short* __restrict__ part) {
    __shared__ __align__(16) short ahis[2][2048];   // [buf][frag4][kg4][lane16][8]
    __shared__ __align__(16) short alos[2][2048];

    const int id   = blockIdx.x;         // 0..415
    const int xcd  = id & 7;             // dispatch round-robin -> XCD
    const int slot = id >> 3;            // 0..51
    const int half = (slot >= MBL2) ? 1 : 0;
    const int kc   = xcd * 2 + half;     // 0..15, pinned to this XCD
    const int mb   = slot - half * MBL2; // 0..25

    const int tid  = threadIdx.x;
    const int w    = tid >> 6;           // nw 0..3
    const int l    = tid & 63;
    const int m    = l & 15;
    const int quad = l >> 4;

    // staging role: thread -> (row sr, k-group skq); covers 8 floats = one kg
    const int sr  = tid >> 2;            // 0..63
    const int skq = tid & 3;             // 0..3
    const float* sp;
    {
        const int r = mb * 64 + sr;
        if (r >= MROW) sp = fpad;        // junk rows, never read downstream
        else {
            const int b = r / 102, rr = r - b * 102;
            if (rr == 0)        sp = fpad + (size_t)b * Dk;
            else if (rr == 101) sp = bpad + (size_t)b * Dk;
            else                sp = x + ((size_t)b * Ss + (rr - 1)) * Dk;
        }
        sp += kc * 512 + skq * 8;
    }
    const int woff = ((sr >> 4) * 4 + skq) * 128 + (sr & 15) * 8;

    // ---- A register ring, depth 2, two float4 per thread ----
    float4 av0[2], av1[2];
    #pragma unroll
    for (int p = 0; p < 2; ++p) {
        av0[p] = *(const float4*)(sp + p * 32);
        av1[p] = *(const float4*)(sp + p * 32 + 4);
    }

    // ---- B register ping-pong, preload step 0 ----
    s8v bh[2][5], bl[2][5];
    {
        const int kg0 = kc * 64 + quad;
        #pragma unroll
        for (int j = 0; j < 5; ++j) {
            const size_t bo = ((size_t)(w * 5 + j) * KG + kg0) * 128 + (size_t)m * 8;
            bh[0][j] = *(const s8v*)(b_hi + bo);
            bl[0][j] = *(const s8v*)(b_lo + bo);
        }
    }

    f4v acc[4][5];
    #pragma unroll
    for (int i = 0; i < 4; ++i)
        #pragma unroll
        for (int j = 0; j < 5; ++j) {
            f4v z = {0.f, 0.f, 0.f, 0.f};
            acc[i][j] = z;
        }

    #pragma unroll
    for (int s = 0; s < 16; ++s) {
        const int cur = s & 1, nxt = cur ^ 1;

        // consume this step's A ring slot
        const float4 va0 = av0[s & 1];
        const float4 va1 = av1[s & 1];

        // B prefetch for NEXT step, issued before this step's barrier
        if (s < 15) {
            const int kgn = kc * 64 + (s + 1) * 4 + quad;
            #pragma unroll
            for (int j = 0; j < 5; ++j) {
                const size_t bo = ((size_t)(w * 5 + j) * KG + kgn) * 128 + (size_t)m * 8;
                bh[nxt][j] = *(const s8v*)(b_hi + bo);
                bl[nxt][j] = *(const s8v*)(b_lo + bo);
            }
        }
        // A prefetch 2 steps ahead into the freed slot
        if (s < 14) {
            av0[s & 1] = *(const float4*)(sp + (s + 2) * 32);
            av1[s & 1] = *(const float4*)(sp + (s + 2) * 32 + 4);
        }

        // convert this step's 8 A values to hi/lo bf16
        const float vv[8] = {va0.x, va0.y, va0.z, va0.w,
                             va1.x, va1.y, va1.z, va1.w};
        s8v h8, l8;
        #pragma unroll
        for (int jj = 0; jj < 8; ++jj) {
            const unsigned u = __float_as_uint(vv[jj]);
            h8[jj] = (short)(unsigned short)(u >> 16);
            l8[jj] = (short)f2bf_rne(vv[jj] - __uint_as_float(u & 0xffff0000u));
        }

        *(s8v*)&ahis[cur][woff] = h8;
        *(s8v*)&alos[cur][woff] = l8;

        // LDS-only barrier: wait own ds ops, sync, leave global loads in flight.
        asm volatile("s_waitcnt lgkmcnt(0)\n\ts_barrier" ::: "memory");

        // A fragments from LDS (4 m-frags, hi+lo)
        s8v ah[4], al[4];
        #pragma unroll
        for (int i = 0; i < 4; ++i) {
            ah[i] = *(const s8v*)&ahis[cur][((i * 4 + quad) * 16 + m) * 8];
            al[i] = *(const s8v*)&alos[cur][((i * 4 + quad) * 16 + m) * 8];
        }

        // 60 MFMAs on register-resident B
        #pragma unroll
        for (int j = 0; j < 5; ++j) {
            const s8v bhv = bh[cur][j], blv = bl[cur][j];
            #pragma unroll
            for (int i = 0; i < 4; ++i)
                acc[i][j] = __builtin_amdgcn_mfma_f32_16x16x32_bf16(ah[i], bhv, acc[i][j], 0, 0, 0);
            #pragma unroll
            for (int i = 0; i < 4; ++i)
                acc[i][j] = __builtin_amdgcn_mfma_f32_16x16x32_bf16(al[i], bhv, acc[i][j], 0, 0, 0);
            #pragma unroll
            for (int i = 0; i < 4; ++i)
                acc[i][j] = __builtin_amdgcn_mfma_f32_16x16x32_bf16(ah[i], blv, acc[i][j], 0, 0, 0);
        }
    }

    // store fp16 partials, row-major [kc][row][col]
    unsigned short* __restrict__ pout = part + (size_t)kc * PSTRIDE;
    #pragma unroll
    for (int i = 0; i < 4; ++i) {
        #pragma unroll
        for (int j = 0; j < 5; ++j) {
            const int col  = (w * 5 + j) * 16 + m;
            const int row0 = mb * 64 + i * 16 + quad * 4;
            #pragma unroll
            for (int r = 0; r < 4; ++r)
                pout[(size_t)(row0 + r) * NCC + col] =
                    __half_as_ushort(__float2half(acc[i][j][r]));
        }
    }
}

// Attention with FUSED KC-reduction (replaces the separate reduce_k kernel).
// Block = (b, chunk of 5 positions); grid 320. Each block stages its 7 qkv
// rows by summing the 16 fp16 partial slices directly (same bytes as the
// old reduce_k path: 21.8 vs 21.7 MB, but one fewer dispatch + no 4.4 MB
// qkv round-trip through HBM/L2).
__global__ __launch_bounds__(256) void attn3(
    const unsigned short* __restrict__ part, float* __restrict__ out) {
    const int blk = blockIdx.x;          // 0..319
    const int b  = blk / (Ss / CH);
    const int c  = blk % (Ss / CH);
    const int s0 = c * CH;
    const int tid = threadIdx.x;

    __shared__ float red[CH + 2][304];   // rows s0..s0+6, cols 0..303
    __shared__ float sc[CH][3];

    // fused reduction: 7 rows x 38 col-groups of 8 = 266 tasks
    for (int idx = tid; idx < (CH + 2) * 38; idx += 256) {
        const int row  = idx / 38;
        const int col0 = (idx % 38) * 8;
        const size_t base = (size_t)(b * 102 + s0 + row) * NCC + col0;
        float sum[8] = {0.f, 0.f, 0.f, 0.f, 0.f, 0.f, 0.f, 0.f};
        #pragma unroll
        for (int k = 0; k < KC; ++k) {
            const s8v u = *(const s8v*)(part + (size_t)k * PSTRIDE + base);
            #pragma unroll
            for (int ii = 0; ii < 8; ++ii)
                sum[ii] += __half2float(__ushort_as_half((unsigned short)u[ii]));
        }
        #pragma unroll
        for (int ii = 0; ii < 8; ++ii) red[row][col0 + ii] = sum[ii];
    }
    __syncthreads();

    // 15 score dots, one per 16-lane group: (ss,u): Q[ss+1].K[ss+u]
    if (tid < CH * 3 * 16) {
        const int d = tid >> 4, g = tid & 15;
        const int ss = d / 3, u = d % 3;
        float ps = 0.0f;
        #pragma unroll
        for (int t = 0; t < 7; ++t) {
            const int p = g + t * 16;
            if (p < Pp) ps += red[ss + 1][p] * red[ss + u][100 + p];
        }
        #pragma unroll
        for (int off = 8; off > 0; off >>= 1) ps += __shfl_down(ps, off, 16);
        if (g == 0) sc[ss][u] = ps;
    }
    __syncthreads();

    for (int idx = tid; idx < CH * Pp; idx += 256) {
        const int ss = idx / Pp, p = idx % Pp;
        const float a0 = sc[ss][0], a1 = sc[ss][1], a2 = sc[ss][2];
        const float mx = fmaxf(a0, fmaxf(a1, a2));
        const float e0 = __expf(a0 - mx), e1 = __expf(a1 - mx), e2 = __expf(a2 - mx);
        const float inv = 1.0f / (e0 + e1 + e2);
        out[(size_t)(b * Ss + s0 + ss) * Pp + p] =
            inv * (e0 * red[ss][200 + p] + e1 * red[ss + 1][200 + p] +
                   e2 * red[ss + 2][200 + p]);
    }
}

extern "C" void kernel_launch(void* const* d_in, const int* in_sizes, int n_in,
                              void* d_out, int out_size, void* d_ws, size_t ws_size,
                              hipStream_t stream) {
    const float* x    = (const float*)d_in[0];
    const float* wq   = (const float*)d_in[1];
    const float* wk   = (const float*)d_in[2];
    const float* wv   = (const float*)d_in[3];
    const float* fpad = (const float*)d_in[4];
    const float* bpad = (const float*)d_in[5];
    float* out = (float*)d_out;

    short* b_hi = (short*)d_ws;                              // 5.24 MB
    short* b_lo = b_hi + B_SEG;                              // 5.24 MB
    unsigned short* part = (unsigned short*)(b_lo + B_SEG);  // 16*1664*320 fp16 = 17.0 MB
    // total ws ~27.5 MB; all buffers fully overwritten, no zeroing needed

    pack_b<<<(NCC * KG) / 256, 256, 0, stream>>>(wq, wk, wv, b_hi, b_lo);
    qkv_gemm<<<MBL2 * KC, 256, 0, stream>>>(x, fpad, bpad, b_hi, b_lo, part);
    attn3<<<Bb * (Ss / CH), 256, 0, stream>>>(part, out);
}